// Round 4
// baseline (150138.745 us; speedup 1.0000x reference)
//
#include <hip/hip_runtime.h>

#define NBATCH 32
#define NPTS   100000
#define NDIM   6
#define KSEL   1024
#define BPB    8                  // blocks per batch
#define NTHREADS 1024
#define TOTT   (BPB * NTHREADS)   // 8192 threads per batch
#define PPT    13                 // ceil(NPTS / TOTT)

// Per-block exchange slot: payload (3 u64) + release/acquire flag. 32 B.
// Layout in d_ws: Slot[2 parity][NBATCH][BPB] = 16 KB.
struct __align__(32) Slot {
    unsigned long long d_bits;    // f64 best distance (bit pattern)
    unsigned long long xy;        // f32 x | f32 y packed
    unsigned long long z_idx;     // f32 z | i32 idx packed
    unsigned int       flag;      // tag = t+1 (release/acquire)
    unsigned int       pad;
};

__global__ void __launch_bounds__(NTHREADS, 1) fps_main(const float* __restrict__ pts,
                                                        float* __restrict__ out,
                                                        Slot* __restrict__ slots)
{
#pragma clang fp contract(off)
    const int bid   = blockIdx.x;
    const int batch = bid & (NBATCH - 1);   // bid%32: a batch's 8 blocks share XCD residue
    const int blk   = bid >> 5;             // 0..7 within batch
    const int tid   = threadIdx.x;
    const int lane  = tid & 63;
    const int wav   = tid >> 6;             // 0..15
    const int tg    = blk * NTHREADS + tid; // 0..8191 within batch

    __shared__ double rdv[16];
    __shared__ int    rii[16];
    __shared__ int    idx_l[KSEL];          // block0 only
    __shared__ double fr0[16], fr1[16], fr2[16];
    __shared__ double sc[4];

    const float* base = pts + (size_t)batch * NPTS * NDIM;

    // ---- point state in registers; dist in f64
    float  px[PPT], py[PPT], pz[PPT];
    double pd[PPT];
#pragma unroll
    for (int k = 0; k < PPT; ++k) {
        int gi = k * TOTT + tg;
        if (gi < NPTS) {
            const float* p = base + (size_t)gi * NDIM;
            px[k] = p[0]; py[k] = p[1]; pz[k] = p[2];
            pd[k] = 1e10;
        } else {
            px[k] = 0.f; py[k] = 0.f; pz[k] = 0.f;
            pd[k] = -1.0;   // never wins (valid dists >= 0; every thread has k=0 valid)
        }
    }

    double lx = (double)base[0], ly = (double)base[1], lz = (double)base[2]; // first = idx 0

    for (int t = 0; t < KSEL - 1; ++t) {
        // ---- f64 distance update + thread-local argmax (numpy order: (xx+yy)+zz, no FMA)
        double bd = -1.0; int bi = 0x7FFFFFFF;
#pragma unroll
        for (int k = 0; k < PPT; ++k) {
            double dx = (double)px[k] - lx;
            double dy = (double)py[k] - ly;
            double dz = (double)pz[k] - lz;
            double dd = ((dx * dx) + (dy * dy)) + (dz * dz);
            double nd = fmin(pd[k], dd);
            pd[k] = nd;
            if (nd > bd) { bd = nd; bi = k * TOTT + tg; }  // strict >: first max in-thread
        }
        // ---- wave reduce (dist desc, idx asc)
#pragma unroll
        for (int off = 32; off >= 1; off >>= 1) {
            double od = __shfl_xor(bd, off, 64);
            int    oi = __shfl_xor(bi, off, 64);
            if (od > bd || (od == bd && oi < bi)) { bd = od; bi = oi; }
        }
        if (lane == 0) { rdv[wav] = bd; rii[wav] = bi; }
        __syncthreads();
        // ---- block reduce (wave 0) -> post slot with payload {d, idx, xyz}
        if (wav == 0) {
            double qd = (lane < 16) ? rdv[lane] : -2.0;
            int    qi = (lane < 16) ? rii[lane] : 0x7FFFFFFF;
#pragma unroll
            for (int off = 8; off >= 1; off >>= 1) {
                double od = __shfl_xor(qd, off, 64);
                int    oi = __shfl_xor(qi, off, 64);
                if (od > qd || (od == qd && oi < qi)) { qd = od; qi = oi; }
            }
            if (lane == 0) {
                const float* wp = base + (size_t)qi * NDIM;   // L2-resident (2.4 MB/batch)
                float wx = wp[0], wy = wp[1], wz = wp[2];
                Slot* s = slots + (((size_t)(t & 1) * NBATCH + batch) * BPB + blk);
                unsigned long long db = (unsigned long long)__double_as_longlong(qd);
                unsigned long long xy = ((unsigned long long)__float_as_uint(wy) << 32)
                                      |  (unsigned long long)__float_as_uint(wx);
                unsigned long long zi = ((unsigned long long)(unsigned)qi << 32)
                                      |  (unsigned long long)__float_as_uint(wz);
                __hip_atomic_store(&s->d_bits, db, __ATOMIC_RELAXED, __HIP_MEMORY_SCOPE_AGENT);
                __hip_atomic_store(&s->xy,     xy, __ATOMIC_RELAXED, __HIP_MEMORY_SCOPE_AGENT);
                __hip_atomic_store(&s->z_idx,  zi, __ATOMIC_RELAXED, __HIP_MEMORY_SCOPE_AGENT);
                __hip_atomic_store(&s->flag, (unsigned)(t + 1), __ATOMIC_RELEASE, __HIP_MEMORY_SCOPE_AGENT);
            }
        }
        // ---- all waves: spin on the 8 flags, reduce slots, in-wave broadcast (no 2nd barrier)
        Slot* srow = slots + ((size_t)(t & 1) * NBATCH + batch) * BPB;
        const unsigned tgt = (unsigned)(t + 1);
        double wd_; int wi_; float wx_, wy_, wz_;
        if (lane < BPB) {
            Slot* s = srow + lane;
            while (__hip_atomic_load(&s->flag, __ATOMIC_ACQUIRE, __HIP_MEMORY_SCOPE_AGENT) != tgt) {}
            unsigned long long db = __hip_atomic_load(&s->d_bits, __ATOMIC_RELAXED, __HIP_MEMORY_SCOPE_AGENT);
            unsigned long long xy = __hip_atomic_load(&s->xy,     __ATOMIC_RELAXED, __HIP_MEMORY_SCOPE_AGENT);
            unsigned long long zi = __hip_atomic_load(&s->z_idx,  __ATOMIC_RELAXED, __HIP_MEMORY_SCOPE_AGENT);
            wd_ = __longlong_as_double((long long)db);
            wx_ = __uint_as_float((unsigned)(xy & 0xFFFFFFFFull));
            wy_ = __uint_as_float((unsigned)(xy >> 32));
            wz_ = __uint_as_float((unsigned)(zi & 0xFFFFFFFFull));
            wi_ = (int)(zi >> 32);
        } else { wd_ = -3.0; wi_ = 0x7FFFFFFF; wx_ = wy_ = wz_ = 0.f; }
#pragma unroll
        for (int off = 4; off >= 1; off >>= 1) {   // reduce within the 8-lane group
            double od = __shfl_xor(wd_, off, 64);
            int    oi = __shfl_xor(wi_, off, 64);
            float  ox = __shfl_xor(wx_, off, 64);
            float  oy = __shfl_xor(wy_, off, 64);
            float  oz = __shfl_xor(wz_, off, 64);
            if (od > wd_ || (od == wd_ && oi < wi_)) { wd_ = od; wi_ = oi; wx_ = ox; wy_ = oy; wz_ = oz; }
        }
        if (blk == 0 && tid == 0) idx_l[t + 1] = wi_;   // tid0 == lane0 of wave0: has winner
        float gx = __shfl(wx_, 0, 64);
        float gy = __shfl(wy_, 0, 64);
        float gz = __shfl(wz_, 0, 64);
        lx = (double)gx; ly = (double)gy; lz = (double)gz;
    }

    if (blk != 0) return;

    // ============ epilogue (block 0 per batch): gather + normalize, f64 accumulation ============
    if (tid == 0) idx_l[0] = 0;
    __syncthreads();

    int si = idx_l[tid];
    const float* sp = base + (size_t)si * NDIM;
    float sx = sp[0], sy = sp[1], szv = sp[2];
    float f3 = sp[3], f4 = sp[4], f5 = sp[5];

    double rx = (double)sx, ry = (double)sy, rz = (double)szv;
#pragma unroll
    for (int off = 32; off >= 1; off >>= 1) {
        rx += __shfl_xor(rx, off, 64);
        ry += __shfl_xor(ry, off, 64);
        rz += __shfl_xor(rz, off, 64);
    }
    if (lane == 0) { fr0[wav] = rx; fr1[wav] = ry; fr2[wav] = rz; }
    __syncthreads();
    if (tid == 0) {
        double tx = 0., ty = 0., tz = 0.;
        for (int i = 0; i < 16; ++i) { tx += fr0[i]; ty += fr1[i]; tz += fr2[i]; }
        sc[0] = tx / (double)KSEL; sc[1] = ty / (double)KSEL; sc[2] = tz / (double)KSEL;
    }
    __syncthreads();
    double ax = (double)sx - sc[0], ay = (double)sy - sc[1], az = (double)szv - sc[2];
    double m = fmax(fabs(ax), fmax(fabs(ay), fabs(az)));
#pragma unroll
    for (int off = 32; off >= 1; off >>= 1) {
        double om = __shfl_xor(m, off, 64);
        m = fmax(m, om);
    }
    if (lane == 0) fr0[wav] = m;
    __syncthreads();
    if (tid == 0) {
        double mm = 0.;
        for (int i = 0; i < 16; ++i) mm = fmax(mm, fr0[i]);
        sc[3] = fmax(mm, 1e-6);
    }
    __syncthreads();
    double scale = sc[3];

    float* ob = out + ((size_t)batch * KSEL + tid) * NDIM;
    ob[0] = (float)(ax / scale);
    ob[1] = (float)(ay / scale);
    ob[2] = (float)(az / scale);
    ob[3] = f3; ob[4] = f4; ob[5] = f5;
}

extern "C" void kernel_launch(void* const* d_in, const int* in_sizes, int n_in,
                              void* d_out, int out_size, void* d_ws, size_t ws_size,
                              hipStream_t stream)
{
    const float* pts = (const float*)d_in[0];
    float* out = (float*)d_out;
    Slot* sl = (Slot*)d_ws;

    void* args[] = { (void*)&pts, (void*)&out, (void*)&sl };
    hipLaunchCooperativeKernel((void*)fps_main, dim3(NBATCH * BPB), dim3(NTHREADS),
                               args, 0, stream);
}

// Round 5
// 17493.929 us; speedup vs baseline: 8.5823x; 8.5823x over previous
//
#include <hip/hip_runtime.h>

#define NBATCH 32
#define NPTS   100000
#define NDIM   6
#define KSEL   1024
#define BPB    8                  // blocks per batch
#define NTHREADS 1024
#define TOTT   (BPB * NTHREADS)   // 8192 threads per batch
#define PPT    13                 // ceil(NPTS / TOTT)

// Per-batch sync record, 512 B: flags (1 line) + per-block payload (32B slots) + winner (1 line).
struct __align__(32) Pay {
    unsigned long long d_bits;    // f64 distance bit pattern
    unsigned long long xy;        // f32 x | f32 y << 32
    unsigned long long z_idx;     // f32 z | i32 idx << 32
    unsigned long long pad;
};
struct __align__(128) BatchSync {
    unsigned int bflag[BPB];      // 32 B — all 8 block flags in one 64B segment
    unsigned int _p0[24];         // pad to 128 B
    Pay pay[BPB];                 // 256 B
    unsigned long long wxy;       // winner payload
    unsigned long long wz_idx;
    unsigned int wflag;
    unsigned int _p1[25];         // pad to 128 B
};                                // total 512 B; x32 batches = 16 KB

__global__ void __launch_bounds__(1024) fps_init(unsigned int* w) {
    int i = blockIdx.x * blockDim.x + threadIdx.x;
    if (i < (int)(NBATCH * sizeof(BatchSync) / 4)) w[i] = 0u;
}

__global__ void __launch_bounds__(NTHREADS, 1) fps_main(const float* __restrict__ pts,
                                                        float* __restrict__ out,
                                                        BatchSync* __restrict__ sync)
{
#pragma clang fp contract(off)
    const int bid   = blockIdx.x;
    const int batch = bid & (NBATCH - 1);
    const int blk   = bid >> 5;             // 0..7 within batch
    const int tid   = threadIdx.x;
    const int lane  = tid & 63;
    const int wav   = tid >> 6;             // 0..15
    const int tg    = blk * NTHREADS + tid; // 0..8191 within batch

    __shared__ double rdv[16];
    __shared__ int    rii[16];
    __shared__ float  lsh[3];               // broadcast winner xyz
    __shared__ int    idx_l[KSEL];          // leader (blk==0) only
    __shared__ double fr0[16], fr1[16], fr2[16];
    __shared__ double sc[4];

    const float* base = pts + (size_t)batch * NPTS * NDIM;
    BatchSync* bs = sync + batch;

    // ---- point state in registers; dist in f64 (bit-exact vs numpy f64 FPS)
    float  px[PPT], py[PPT], pz[PPT];
    double pd[PPT];
#pragma unroll
    for (int k = 0; k < PPT; ++k) {
        int gi = k * TOTT + tg;
        if (gi < NPTS) {
            const float* p = base + (size_t)gi * NDIM;
            px[k] = p[0]; py[k] = p[1]; pz[k] = p[2];
            pd[k] = 1e10;
        } else {
            px[k] = 0.f; py[k] = 0.f; pz[k] = 0.f;
            pd[k] = -1.0;   // never wins (valid dists >= 0)
        }
    }

    double lx = (double)base[0], ly = (double)base[1], lz = (double)base[2]; // first = idx 0

    for (int t = 0; t < KSEL - 1; ++t) {
        const unsigned tag = (unsigned)(t + 1);
        // ---- f64 distance update + thread-local argmax (numpy order: (xx+yy)+zz, no FMA)
        double bd = -1.0; int bi = 0x7FFFFFFF;
#pragma unroll
        for (int k = 0; k < PPT; ++k) {
            double dx = (double)px[k] - lx;
            double dy = (double)py[k] - ly;
            double dz = (double)pz[k] - lz;
            double dd = ((dx * dx) + (dy * dy)) + (dz * dz);
            double nd = fmin(pd[k], dd);
            pd[k] = nd;
            if (nd > bd) { bd = nd; bi = k * TOTT + tg; }  // strict >: first max in-thread
        }
        // ---- wave reduce (dist desc, idx asc)
#pragma unroll
        for (int off = 32; off >= 1; off >>= 1) {
            double od = __shfl_xor(bd, off, 64);
            int    oi = __shfl_xor(bi, off, 64);
            if (od > bd || (od == bd && oi < bi)) { bd = od; bi = oi; }
        }
        if (lane == 0) { rdv[wav] = bd; rii[wav] = bi; }
        __syncthreads();

        if (wav == 0) {
            // ---- block reduce over 16 wave winners
            double qd = (lane < 16) ? rdv[lane] : -2.0;
            int    qi = (lane < 16) ? rii[lane] : 0x7FFFFFFF;
#pragma unroll
            for (int off = 8; off >= 1; off >>= 1) {
                double od = __shfl_xor(qd, off, 64);
                int    oi = __shfl_xor(qi, off, 64);
                if (od > qd || (od == qd && oi < qi)) { qd = od; qi = oi; }
            }
            // ---- post this block's winner {d, xyz, idx}
            if (lane == 0) {
                const float* wp = base + (size_t)qi * NDIM;   // L2-resident
                unsigned long long db = (unsigned long long)__double_as_longlong(qd);
                unsigned long long xy = ((unsigned long long)__float_as_uint(wp[1]) << 32)
                                      |  (unsigned long long)__float_as_uint(wp[0]);
                unsigned long long zi = ((unsigned long long)(unsigned)qi << 32)
                                      |  (unsigned long long)__float_as_uint(wp[2]);
                Pay* p = &bs->pay[blk];
                __hip_atomic_store(&p->d_bits, db, __ATOMIC_RELAXED, __HIP_MEMORY_SCOPE_AGENT);
                __hip_atomic_store(&p->xy,     xy, __ATOMIC_RELAXED, __HIP_MEMORY_SCOPE_AGENT);
                __hip_atomic_store(&p->z_idx,  zi, __ATOMIC_RELAXED, __HIP_MEMORY_SCOPE_AGENT);
                __hip_atomic_store(&bs->bflag[blk], tag, __ATOMIC_RELEASE, __HIP_MEMORY_SCOPE_AGENT);
            }
            if (blk == 0) {
                // ---- leader: 8 lanes poll the 8 flags (one 64B segment), reduce, post winner
                double wd_; int wi_; unsigned long long pxy, pzi;
                if (lane < BPB) {
                    while (__hip_atomic_load(&bs->bflag[lane], __ATOMIC_ACQUIRE,
                                             __HIP_MEMORY_SCOPE_AGENT) != tag)
                        __builtin_amdgcn_s_sleep(1);
                    Pay* p = &bs->pay[lane];
                    unsigned long long db = __hip_atomic_load(&p->d_bits, __ATOMIC_RELAXED, __HIP_MEMORY_SCOPE_AGENT);
                    pxy = __hip_atomic_load(&p->xy,    __ATOMIC_RELAXED, __HIP_MEMORY_SCOPE_AGENT);
                    pzi = __hip_atomic_load(&p->z_idx, __ATOMIC_RELAXED, __HIP_MEMORY_SCOPE_AGENT);
                    wd_ = __longlong_as_double((long long)db);
                    wi_ = (int)(pzi >> 32);
                } else { wd_ = -3.0; wi_ = 0x7FFFFFFF; pxy = 0ull; pzi = 0ull; }
#pragma unroll
                for (int off = 4; off >= 1; off >>= 1) {
                    double od = __shfl_xor(wd_, off, 64);
                    int    oi = __shfl_xor(wi_, off, 64);
                    unsigned long long oxy = __shfl_xor(pxy, off, 64);
                    unsigned long long ozi = __shfl_xor(pzi, off, 64);
                    if (od > wd_ || (od == wd_ && oi < wi_)) { wd_ = od; wi_ = oi; pxy = oxy; pzi = ozi; }
                }
                if (lane == 0) {
                    __hip_atomic_store(&bs->wxy,    pxy, __ATOMIC_RELAXED, __HIP_MEMORY_SCOPE_AGENT);
                    __hip_atomic_store(&bs->wz_idx, pzi, __ATOMIC_RELAXED, __HIP_MEMORY_SCOPE_AGENT);
                    __hip_atomic_store(&bs->wflag,  tag, __ATOMIC_RELEASE, __HIP_MEMORY_SCOPE_AGENT);
                    lsh[0] = __uint_as_float((unsigned)(pxy & 0xFFFFFFFFull));
                    lsh[1] = __uint_as_float((unsigned)(pxy >> 32));
                    lsh[2] = __uint_as_float((unsigned)(pzi & 0xFFFFFFFFull));
                    idx_l[t + 1] = wi_;
                }
            } else {
                // ---- follower: single lane polls the winner flag
                if (lane == 0) {
                    while (__hip_atomic_load(&bs->wflag, __ATOMIC_ACQUIRE,
                                             __HIP_MEMORY_SCOPE_AGENT) != tag)
                        __builtin_amdgcn_s_sleep(1);
                    unsigned long long pxy = __hip_atomic_load(&bs->wxy,    __ATOMIC_RELAXED, __HIP_MEMORY_SCOPE_AGENT);
                    unsigned long long pzi = __hip_atomic_load(&bs->wz_idx, __ATOMIC_RELAXED, __HIP_MEMORY_SCOPE_AGENT);
                    lsh[0] = __uint_as_float((unsigned)(pxy & 0xFFFFFFFFull));
                    lsh[1] = __uint_as_float((unsigned)(pxy >> 32));
                    lsh[2] = __uint_as_float((unsigned)(pzi & 0xFFFFFFFFull));
                }
            }
        }
        __syncthreads();
        lx = (double)lsh[0]; ly = (double)lsh[1]; lz = (double)lsh[2];
    }

    if (blk != 0) return;

    // ============ epilogue (leader block per batch): gather + normalize, f64 accumulation ============
    if (tid == 0) idx_l[0] = 0;
    __syncthreads();

    int si = idx_l[tid];
    const float* sp = base + (size_t)si * NDIM;
    float sx = sp[0], sy = sp[1], szv = sp[2];
    float f3 = sp[3], f4 = sp[4], f5 = sp[5];

    double rx = (double)sx, ry = (double)sy, rz = (double)szv;
#pragma unroll
    for (int off = 32; off >= 1; off >>= 1) {
        rx += __shfl_xor(rx, off, 64);
        ry += __shfl_xor(ry, off, 64);
        rz += __shfl_xor(rz, off, 64);
    }
    if (lane == 0) { fr0[wav] = rx; fr1[wav] = ry; fr2[wav] = rz; }
    __syncthreads();
    if (tid == 0) {
        double tx = 0., ty = 0., tz = 0.;
        for (int i = 0; i < 16; ++i) { tx += fr0[i]; ty += fr1[i]; tz += fr2[i]; }
        sc[0] = tx / (double)KSEL; sc[1] = ty / (double)KSEL; sc[2] = tz / (double)KSEL;
    }
    __syncthreads();
    double ax = (double)sx - sc[0], ay = (double)sy - sc[1], az = (double)szv - sc[2];
    double m = fmax(fabs(ax), fmax(fabs(ay), fabs(az)));
#pragma unroll
    for (int off = 32; off >= 1; off >>= 1) {
        double om = __shfl_xor(m, off, 64);
        m = fmax(m, om);
    }
    if (lane == 0) fr0[wav] = m;
    __syncthreads();
    if (tid == 0) {
        double mm = 0.;
        for (int i = 0; i < 16; ++i) mm = fmax(mm, fr0[i]);
        sc[3] = fmax(mm, 1e-6);
    }
    __syncthreads();
    double scale = sc[3];

    float* ob = out + ((size_t)batch * KSEL + tid) * NDIM;
    ob[0] = (float)(ax / scale);
    ob[1] = (float)(ay / scale);
    ob[2] = (float)(az / scale);
    ob[3] = f3; ob[4] = f4; ob[5] = f5;
}

extern "C" void kernel_launch(void* const* d_in, const int* in_sizes, int n_in,
                              void* d_out, int out_size, void* d_ws, size_t ws_size,
                              hipStream_t stream)
{
    const float* pts = (const float*)d_in[0];
    float* out = (float*)d_out;
    BatchSync* bs = (BatchSync*)d_ws;

    hipLaunchKernelGGL(fps_init, dim3(4), dim3(1024), 0, stream, (unsigned int*)d_ws);

    void* args[] = { (void*)&pts, (void*)&out, (void*)&bs };
    hipLaunchCooperativeKernel((void*)fps_main, dim3(NBATCH * BPB), dim3(NTHREADS),
                               args, 0, stream);
}

// Round 6
// 4615.818 us; speedup vs baseline: 32.5270x; 3.7900x over previous
//
#include <hip/hip_runtime.h>

#define NBATCH 32
#define NPTS   100000
#define NDIM   6
#define KSEL   1024
#define BPB    8                  // blocks per batch
#define NTHREADS 1024
#define TOTT   (BPB * NTHREADS)   // 8192 threads per batch
#define PPT    13                 // ceil(NPTS / TOTT)

// Fence-free exchange state in d_ws. All accesses are RELAXED agent-scope atomics;
// ordering is enforced by s_waitcnt vmcnt(0) on the writer and data-flow on readers.
struct __align__(32) BlkPost {            // 32 B per block post
    unsigned long long d_bits;            // f64 best distance (bit pattern)
    unsigned long long xy;                // f32 x | f32 y << 32
    unsigned long long z_idx;             // f32 z | i32 idx << 32
    unsigned long long pad;
};
struct __align__(64) FlagRow {            // one 64B line per batch per parity
    unsigned f[16];                       // f[0..7] used
};
struct Ws {
    BlkPost post[2][NBATCH][BPB];         // 16 KB
    FlagRow flags[2][NBATCH];             // 4 KB
};

__global__ void __launch_bounds__(1024) fps_init(unsigned int* w) {
    int i = blockIdx.x * blockDim.x + threadIdx.x;
    if (i < (int)(sizeof(Ws) / 4)) w[i] = 0u;
}

__global__ void __launch_bounds__(NTHREADS, 1) fps_main(const float* __restrict__ pts,
                                                        float* __restrict__ out,
                                                        Ws* __restrict__ ws)
{
#pragma clang fp contract(off)
    const int bid   = blockIdx.x;
    const int batch = bid & (NBATCH - 1);   // a batch's 8 blocks share bid%8 residue (XCD locality)
    const int blk   = bid >> 5;             // 0..7 within batch
    const int tid   = threadIdx.x;
    const int lane  = tid & 63;
    const int wav   = tid >> 6;             // 0..15
    const int tg    = blk * NTHREADS + tid; // 0..8191 within batch

    __shared__ double rdv[16];
    __shared__ int    rii[16];
    __shared__ float  lsh[3];               // broadcast winner xyz
    __shared__ int    idx_l[KSEL];          // leader (blk==0) only
    __shared__ double fr0[16], fr1[16], fr2[16];
    __shared__ double sc[4];

    const float* base = pts + (size_t)batch * NPTS * NDIM;

    // ---- point state in registers; dist in f64 (bit-exact vs numpy f64 FPS)
    float  px[PPT], py[PPT], pz[PPT];
    double pd[PPT];
#pragma unroll
    for (int k = 0; k < PPT; ++k) {
        int gi = k * TOTT + tg;
        if (gi < NPTS) {
            const float* p = base + (size_t)gi * NDIM;
            px[k] = p[0]; py[k] = p[1]; pz[k] = p[2];
            pd[k] = 1e10;
        } else {
            px[k] = 0.f; py[k] = 0.f; pz[k] = 0.f;
            pd[k] = -1.0;   // never wins (valid dists >= 0)
        }
    }

    double lx = (double)base[0], ly = (double)base[1], lz = (double)base[2]; // first = idx 0

    for (int t = 0; t < KSEL - 1; ++t) {
        const unsigned tag = (unsigned)(t + 1);
        const int par = t & 1;
        // ---- f64 distance update + thread-local argmax (numpy order: (xx+yy)+zz, no FMA)
        double bd = -1.0; int bi = 0x7FFFFFFF;
#pragma unroll
        for (int k = 0; k < PPT; ++k) {
            double dx = (double)px[k] - lx;
            double dy = (double)py[k] - ly;
            double dz = (double)pz[k] - lz;
            double dd = ((dx * dx) + (dy * dy)) + (dz * dz);
            double nd = fmin(pd[k], dd);
            pd[k] = nd;
            if (nd > bd) { bd = nd; bi = k * TOTT + tg; }  // strict >: first max in-thread
        }
        // ---- wave reduce (dist desc, idx asc)
#pragma unroll
        for (int off = 32; off >= 1; off >>= 1) {
            double od = __shfl_xor(bd, off, 64);
            int    oi = __shfl_xor(bi, off, 64);
            if (od > bd || (od == bd && oi < bi)) { bd = od; bi = oi; }
        }
        if (lane == 0) { rdv[wav] = bd; rii[wav] = bi; }
        __syncthreads();

        if (wav == 0) {
            // ---- block reduce over 16 wave winners (lanes 0..15 hold them)
            double qd = (lane < 16) ? rdv[lane] : -2.0;
            int    qi = (lane < 16) ? rii[lane] : 0x7FFFFFFF;
#pragma unroll
            for (int off = 8; off >= 1; off >>= 1) {
                double od = __shfl_xor(qd, off, 64);
                int    oi = __shfl_xor(qi, off, 64);
                if (od > qd || (od == qd && oi < qi)) { qd = od; qi = oi; }
            }
            // ---- post this block's winner {d, xyz, idx}: relaxed payload, vmcnt fence, relaxed flag
            if (lane == 0) {
                const float* wp = base + (size_t)qi * NDIM;   // L2-resident
                unsigned long long db = (unsigned long long)__double_as_longlong(qd);
                unsigned long long xy = ((unsigned long long)__float_as_uint(wp[1]) << 32)
                                      |  (unsigned long long)__float_as_uint(wp[0]);
                unsigned long long zi = ((unsigned long long)(unsigned)qi << 32)
                                      |  (unsigned long long)__float_as_uint(wp[2]);
                BlkPost* p = &ws->post[par][batch][blk];
                __hip_atomic_store(&p->d_bits, db, __ATOMIC_RELAXED, __HIP_MEMORY_SCOPE_AGENT);
                __hip_atomic_store(&p->xy,     xy, __ATOMIC_RELAXED, __HIP_MEMORY_SCOPE_AGENT);
                __hip_atomic_store(&p->z_idx,  zi, __ATOMIC_RELAXED, __HIP_MEMORY_SCOPE_AGENT);
                // store-release without cache-maintenance: wait for payload store acks,
                // then publish the tag. (This is LLVM's release lowering minus the L2 flush.)
                asm volatile("s_waitcnt vmcnt(0)" ::: "memory");
                __hip_atomic_store(&ws->flags[par][batch].f[blk], tag,
                                   __ATOMIC_RELAXED, __HIP_MEMORY_SCOPE_AGENT);
            }
            // ---- single-hop: lanes 0..7 spin (relaxed, no invalidates) on the 8 flags
            double wd_; int wi_; unsigned long long pxy, pzi;
            if (lane < BPB) {
                unsigned* fp = &ws->flags[par][batch].f[lane];
                while (__hip_atomic_load(fp, __ATOMIC_RELAXED, __HIP_MEMORY_SCOPE_AGENT) != tag) {}
                asm volatile("" ::: "memory");   // keep payload loads after the poll
                BlkPost* p = &ws->post[par][batch][lane];
                unsigned long long db = __hip_atomic_load(&p->d_bits, __ATOMIC_RELAXED, __HIP_MEMORY_SCOPE_AGENT);
                pxy = __hip_atomic_load(&p->xy,    __ATOMIC_RELAXED, __HIP_MEMORY_SCOPE_AGENT);
                pzi = __hip_atomic_load(&p->z_idx, __ATOMIC_RELAXED, __HIP_MEMORY_SCOPE_AGENT);
                wd_ = __longlong_as_double((long long)db);
                wi_ = (int)(pzi >> 32);
            } else { wd_ = -3.0; wi_ = 0x7FFFFFFF; pxy = 0ull; pzi = 0ull; }
#pragma unroll
            for (int off = 4; off >= 1; off >>= 1) {   // reduce within lanes 0..7
                double od = __shfl_xor(wd_, off, 64);
                int    oi = __shfl_xor(wi_, off, 64);
                unsigned long long oxy = __shfl_xor(pxy, off, 64);
                unsigned long long ozi = __shfl_xor(pzi, off, 64);
                if (od > wd_ || (od == wd_ && oi < wi_)) { wd_ = od; wi_ = oi; pxy = oxy; pzi = ozi; }
            }
            if (lane == 0) {
                lsh[0] = __uint_as_float((unsigned)(pxy & 0xFFFFFFFFull));
                lsh[1] = __uint_as_float((unsigned)(pxy >> 32));
                lsh[2] = __uint_as_float((unsigned)(pzi & 0xFFFFFFFFull));
                if (blk == 0) idx_l[t + 1] = wi_;
            }
        }
        __syncthreads();
        lx = (double)lsh[0]; ly = (double)lsh[1]; lz = (double)lsh[2];
    }

    if (blk != 0) return;

    // ============ epilogue (leader block per batch): gather + normalize, f64 accumulation ============
    if (tid == 0) idx_l[0] = 0;
    __syncthreads();

    int si = idx_l[tid];
    const float* sp = base + (size_t)si * NDIM;
    float sx = sp[0], sy = sp[1], szv = sp[2];
    float f3 = sp[3], f4 = sp[4], f5 = sp[5];

    double rx = (double)sx, ry = (double)sy, rz = (double)szv;
#pragma unroll
    for (int off = 32; off >= 1; off >>= 1) {
        rx += __shfl_xor(rx, off, 64);
        ry += __shfl_xor(ry, off, 64);
        rz += __shfl_xor(rz, off, 64);
    }
    if (lane == 0) { fr0[wav] = rx; fr1[wav] = ry; fr2[wav] = rz; }
    __syncthreads();
    if (tid == 0) {
        double tx = 0., ty = 0., tz = 0.;
        for (int i = 0; i < 16; ++i) { tx += fr0[i]; ty += fr1[i]; tz += fr2[i]; }
        sc[0] = tx / (double)KSEL; sc[1] = ty / (double)KSEL; sc[2] = tz / (double)KSEL;
    }
    __syncthreads();
    double ax = (double)sx - sc[0], ay = (double)sy - sc[1], az = (double)szv - sc[2];
    double m = fmax(fabs(ax), fmax(fabs(ay), fabs(az)));
#pragma unroll
    for (int off = 32; off >= 1; off >>= 1) {
        double om = __shfl_xor(m, off, 64);
        m = fmax(m, om);
    }
    if (lane == 0) fr0[wav] = m;
    __syncthreads();
    if (tid == 0) {
        double mm = 0.;
        for (int i = 0; i < 16; ++i) mm = fmax(mm, fr0[i]);
        sc[3] = fmax(mm, 1e-6);
    }
    __syncthreads();
    double scale = sc[3];

    float* ob = out + ((size_t)batch * KSEL + tid) * NDIM;
    ob[0] = (float)(ax / scale);
    ob[1] = (float)(ay / scale);
    ob[2] = (float)(az / scale);
    ob[3] = f3; ob[4] = f4; ob[5] = f5;
}

extern "C" void kernel_launch(void* const* d_in, const int* in_sizes, int n_in,
                              void* d_out, int out_size, void* d_ws, size_t ws_size,
                              hipStream_t stream)
{
    const float* pts = (const float*)d_in[0];
    float* out = (float*)d_out;
    Ws* ws = (Ws*)d_ws;

    hipLaunchKernelGGL(fps_init, dim3(8), dim3(1024), 0, stream, (unsigned int*)d_ws);

    void* args[] = { (void*)&pts, (void*)&out, (void*)&ws };
    hipLaunchCooperativeKernel((void*)fps_main, dim3(NBATCH * BPB), dim3(NTHREADS),
                               args, 0, stream);
}